// Round 5
// baseline (237.601 us; speedup 1.0000x reference)
//
#include <hip/hip_runtime.h>
#include <hip/hip_fp8.h>
#include <cstdint>
#include <cmath>

// Problem constants
#define B_   4
#define C_   512
#define HW_  4096
#define G_   32
#define CPG_ 16
#define EPS_ 1e-6f
#define SCALE_ 0.04419417382415922f  // 1/sqrt(512)
#define PSCALE_ 0.0625f              // P pre-scale; cancels in acc/rowsum ratio
#define SEXPC_ 0.063758715306f       // SCALE * log2(e): exp(a*S)*2^-4 = 2^(a*SEXPC - 4)

// ---------------------------------------------------------------------------
// Column permutation (sigma): GEMM epilogues store outputs in the MFMA
// C-layout packed order. Within each 64-col group, stored position
// p = fr*4 + j holds true column c = j*16 + fr. Invariant under contraction
// as long as producer & consumer agree.
//
// Weight scaling: fp8 weights are stored x16; the MFMA e8m0 scale operand
// 0x7B (= 2^-4) folds the 1/16 back in HW. Same trick for hmT8.
//
// R13 (post-mortem R12): every pipe sits at 25-33% (MfmaUtil 24, VALU 33,
// L2 27%, LDS ~30%) -> latency-bound serial chain, not throughput-bound;
// VALU shave matched its counter prediction but time unmoved. This is
// m233's "2-phase stall". Fix = the m201 8-phase 256^2 template, ported to
// MX-fp8 (BK=128) for sexp: 8 waves, per K-tile 4 sub-phases of
// {12 ds_read | 4 cp16 stage-ahead -> barrier -> lgkmcnt(0) -> 8 MFMA
// (setprio) -> barrier}; tile t+1 fully issued by phase 1 so the per-tile
// vmcnt(0) (after phase 3 MFMAs) waits on ~900-cycle-old loads == free.
// pv/qkv/proj keep the 128^2 2-phase path this round (one structural change).
// ---------------------------------------------------------------------------

typedef __bf16 bf16_t;
typedef __bf16 bf16x8 __attribute__((ext_vector_type(8)));
typedef float  f32x4  __attribute__((ext_vector_type(4)));
typedef int    i32x4  __attribute__((ext_vector_type(4)));
typedef int    i32x8  __attribute__((ext_vector_type(8)));
typedef unsigned int u32;
typedef __hip_fp8_e4m3 fp8_t;  // OCP e4m3fn on gfx950

// Async global->LDS copy, 16B per lane. LDS dest is wave-uniform base + lane*16.
__device__ __forceinline__ void cp16(const void* g, void* l) {
  __builtin_amdgcn_global_load_lds((__attribute__((address_space(1))) u32*)(g),
                                   (__attribute__((address_space(3))) u32*)(l),
                                   16, 0, 0);
}

// Raw v_exp_f32 (2^x). s_nop 1 covers the trans->consumer wait-state
// conservatively (inline asm is opaque to the hazard recognizer).
__device__ __forceinline__ float fexp2(float x) {
  float r;
  asm("v_exp_f32 %0, %1\n\ts_nop 1" : "=v"(r) : "v"(x));
  return r;
}

__device__ __forceinline__ void zero_acc(f32x4 acc[4][4]) {
  f32x4 z = {0.f, 0.f, 0.f, 0.f};
#pragma unroll
  for (int i = 0; i < 4; ++i)
#pragma unroll
    for (int j = 0; j < 4; ++j) acc[i][j] = z;
}

// MX-fp8 BT GEMM mainloop (BK=128): mfma_scale_f32_16x16x128_f8f6f4, fmt 0
// (e4m3), per-operand e8m0 scales SA/SB (0x7F = 1.0, 0x7B = 2^-4).
// LDS rows are 128 B (8 chunks); chunk-rotation swizzle mod 8 keeps staging
// and the paired ds_read_b128 fragment reads at the LDS bank floor.
// Double-buffered (2x16 KB per operand, caller-provided LDS), counted vmcnt.
template <bool ROWSUM, int SA = 0x7F, int SB = 0x7F>
__device__ __forceinline__ void gemm_bt_mx(const unsigned char* __restrict__ A,
                                           const unsigned char* __restrict__ B,
                                           int K, int lda, int ldb,
                                           f32x4 acc[4][4], f32x4 accl[4],
                                           unsigned char* AsB, unsigned char* BsB) {
  const int tid  = threadIdx.x;
  const int wave = tid >> 6;
  const int lane = tid & 63;
  const int wm = (wave >> 1) * 64;
  const int wn = (wave & 1) * 64;
  // staging: per cp16 call lane covers row (lane>>3), LDS chunk (lane&7);
  // rotation: LDS chunk c of row r holds global chunk (c - r) & 7.
  const int srow = lane >> 3;
  const int gch  = ((lane & 7) - srow) & 7;
  const unsigned char* gA = A + (size_t)(wave * 32 + srow) * lda + gch * 16;
  const unsigned char* gB = B + (size_t)(wave * 32 + srow) * ldb + gch * 16;
  const int lofs = wave * 32 * 128;
  const int fr = lane & 15;
  const int q  = lane >> 4;
  // lane wants global chunks 2q, 2q+1 of its row (32 B = K-128 fragment)
  const int co0 = ((2 * q     + fr) & 7) * 16;
  const int co1 = ((2 * q + 1 + fr) & 7) * 16;
  const i32x8 vones = {0x38383838, 0x38383838, 0x38383838, 0x38383838,
                       0x38383838, 0x38383838, 0x38383838, 0x38383838};

  const int nT = K >> 7;
  // prologue: stage tile 0 into buffer 0
#pragma unroll
  for (int cc = 0; cc < 4; ++cc) {
    cp16(gA + (size_t)(cc * 8) * lda, AsB + lofs + cc * 1024);
    cp16(gB + (size_t)(cc * 8) * ldb, BsB + lofs + cc * 1024);
  }
  gA += 128; gB += 128;

#pragma unroll 1
  for (int t = 0; t < nT; ++t) {
    const int cur = t & 1;
    if (t + 1 < nT) {
      // stage tile t+1 into the other buffer; it flies across this tile's
      // compute and is drained by next iteration's vmcnt(8).
#pragma unroll
      for (int cc = 0; cc < 4; ++cc) {
        cp16(gA + (size_t)(cc * 8) * lda, AsB + (cur ^ 1) * 16384 + lofs + cc * 1024);
        cp16(gB + (size_t)(cc * 8) * ldb, BsB + (cur ^ 1) * 16384 + lofs + cc * 1024);
      }
      gA += 128; gB += 128;
      asm volatile("s_waitcnt vmcnt(8)" ::: "memory");  // tile t resident
    } else {
      asm volatile("s_waitcnt vmcnt(0)" ::: "memory");  // last tile resident
    }
    __builtin_amdgcn_s_barrier();   // tile t visible to all waves

    i32x8 a[4], b[4];
    const unsigned char* Ab = AsB + cur * 16384;
    const unsigned char* Bb = BsB + cur * 16384;
#pragma unroll
    for (int i = 0; i < 4; ++i) {
      const int ro = (wm + i * 16 + fr) * 128;
      i32x4 lo = *(const i32x4*)(Ab + ro + co0);
      i32x4 hi = *(const i32x4*)(Ab + ro + co1);
      a[i] = __builtin_shufflevector(lo, hi, 0, 1, 2, 3, 4, 5, 6, 7);
    }
#pragma unroll
    for (int j = 0; j < 4; ++j) {
      const int ro = (wn + j * 16 + fr) * 128;
      i32x4 lo = *(const i32x4*)(Bb + ro + co0);
      i32x4 hi = *(const i32x4*)(Bb + ro + co1);
      b[j] = __builtin_shufflevector(lo, hi, 0, 1, 2, 3, 4, 5, 6, 7);
    }
    __builtin_amdgcn_s_setprio(1);
#pragma unroll
    for (int i = 0; i < 4; ++i) {
#pragma unroll
      for (int j = 0; j < 4; ++j)
        acc[i][j] = __builtin_amdgcn_mfma_scale_f32_16x16x128_f8f6f4(
            a[i], b[j], acc[i][j], 0, 0, 0, SA, 0, SB);
      if (ROWSUM)
        accl[i] = __builtin_amdgcn_mfma_scale_f32_16x16x128_f8f6f4(
            a[i], vones, accl[i], 0, 0, 0, SA, 0, 0x7F);
    }
    __builtin_amdgcn_s_setprio(0);
    __builtin_amdgcn_s_barrier();   // all reads of buf[cur] done
  }
}

// ---------------- prep: GroupNorm partials + weight casts (merged) ----------

// blocks [0,1024): partial GN stats (8 hw-chunks per group, 2 atomics each).
// blocks [1024,2048): wqkv8 = fp8(qkv_w*16) plain; wproj8 = fp8(proj_w*16)
// with sigma-permuted c columns.
__global__ void __launch_bounds__(256) prep_kernel(const float* __restrict__ x,
                                                   float* __restrict__ stats,
                                                   const float* __restrict__ qkv_w,
                                                   const float* __restrict__ proj_w,
                                                   fp8_t* __restrict__ wqkv8,
                                                   fp8_t* __restrict__ wproj8) {
  __shared__ float rs[256], rss[256];
  const int n = blockIdx.x;
  if (n < 1024) {
    const int bg = n >> 3;       // group id 0..127
    const int ch = n & 7;        // hw chunk 0..7
    const float4* base = (const float4*)(x + (size_t)bg * (CPG_ * HW_)) +
                         (size_t)ch * (CPG_ * HW_ / 4 / 8);
    float s = 0.f, ss = 0.f;
    for (int i = threadIdx.x; i < CPG_ * HW_ / 4 / 8; i += 256) {
      float4 v = base[i];
      s  += v.x + v.y + v.z + v.w;
      ss += v.x * v.x + v.y * v.y + v.z * v.z + v.w * v.w;
    }
    rs[threadIdx.x] = s; rss[threadIdx.x] = ss;
    __syncthreads();
    for (int st = 128; st > 0; st >>= 1) {
      if ((int)threadIdx.x < st) {
        rs[threadIdx.x]  += rs[threadIdx.x + st];
        rss[threadIdx.x] += rss[threadIdx.x + st];
      }
      __syncthreads();
    }
    if (threadIdx.x == 0) {
      atomicAdd(&stats[bg * 2 + 0], rs[0]);
      atomicAdd(&stats[bg * 2 + 1], rss[0]);
    }
  } else {
    const int idx = (n - 1024) * 256 + threadIdx.x;   // quad index
    const int t = idx * 4;
    const int nq = 1536 * 512;
    if (t < nq) {
      u32 dw = 0;
      dw = (u32)__builtin_amdgcn_cvt_pk_fp8_f32(qkv_w[t] * 16.f, qkv_w[t + 1] * 16.f, (int)dw, false);
      dw = (u32)__builtin_amdgcn_cvt_pk_fp8_f32(qkv_w[t + 2] * 16.f, qkv_w[t + 3] * 16.f, (int)dw, true);
      *(u32*)((unsigned char*)wqkv8 + t) = dw;
    } else {
      const int tt = t - nq;          // o*512 + p, p multiple of 4
      const int o = tt >> 9;
      const int p = tt & 511;
      float v[4];
#pragma unroll
      for (int e = 0; e < 4; ++e) {
        const int pe = p + e;
        const int off = pe & 63;
        const int c = (pe & ~63) + ((off & 3) << 4) + (off >> 2);  // sigma(pe)
        v[e] = proj_w[(o << 9) + c] * 16.f;
      }
      u32 dw = 0;
      dw = (u32)__builtin_amdgcn_cvt_pk_fp8_f32(v[0], v[1], (int)dw, false);
      dw = (u32)__builtin_amdgcn_cvt_pk_fp8_f32(v[2], v[3], (int)dw, true);
      *(u32*)((unsigned char*)wproj8 + tt) = dw;
    }
  }
}

// normalize + transpose: x[b][c][i] (fp32) -> xnT8[b][i][c] (fp8, plain order)
__global__ void __launch_bounds__(256) norm_tr_kernel(const float* __restrict__ x,
                                                      const float* __restrict__ stats,
                                                      const float* __restrict__ nw,
                                                      const float* __restrict__ nb,
                                                      fp8_t* __restrict__ xnT8) {
  __shared__ float tile[64][65];   // [c_off][i_off]
  const int b  = blockIdx.z;
  const int i0 = blockIdx.x * 64;   // hw
  const int c0 = blockIdx.y * 64;   // channel
  const int tx = threadIdx.x & 63;
  const int ty = threadIdx.x >> 6;  // 0..3
  const int cbase = c0 + ty * 16;
  const int g = cbase >> 4;         // group const across r (16 channels per ty)
  const float inv = 1.f / (float)(CPG_ * HW_);
  const float sum  = stats[(b * G_ + g) * 2 + 0];
  const float ssum = stats[(b * G_ + g) * 2 + 1];
  const float mean = sum * inv;
  const float rstd = rsqrtf(ssum * inv - mean * mean + EPS_);
#pragma unroll
  for (int r = 0; r < 16; ++r) {
    const int c = cbase + r;
    float v = x[((size_t)b * C_ + c) * HW_ + i0 + tx];
    tile[ty * 16 + r][tx] = (v - mean) * rstd * nw[c] + nb[c];
  }
  __syncthreads();
  const int il = threadIdx.x >> 2;
  const int q4 = threadIdx.x & 3;
#pragma unroll
  for (int m = 0; m < 4; ++m) {
    const int cq = q4 + m * 4;     // 0..15
    u32 dw = 0;
    dw = (u32)__builtin_amdgcn_cvt_pk_fp8_f32(tile[cq * 4 + 0][il], tile[cq * 4 + 1][il], (int)dw, false);
    dw = (u32)__builtin_amdgcn_cvt_pk_fp8_f32(tile[cq * 4 + 2][il], tile[cq * 4 + 3][il], (int)dw, true);
    *(u32*)((unsigned char*)xnT8 + ((size_t)b * HW_ + i0 + il) * C_ + c0 + cq * 4) = dw;
  }
}

// ---------------- GEMM kernels ----------------

// Merged qk+v projections (saves a dispatch; v's small grid rides qk's tail).
// blocks [0,1024): QKt8[b][i][sig o] = fp8( xnT8 . wqkv8*2^-4 + bias )
// blocks [1024,1536): V8[b][c][sig j] = fp8( wqkv8_v*2^-4 . xnT8 + bias )
__global__ void __launch_bounds__(256) qkv_gemm_kernel(const fp8_t* __restrict__ xnT8,
                                                       const fp8_t* __restrict__ wqkv8,
                                                       const float* __restrict__ qkv_b,
                                                       fp8_t* __restrict__ QKt8,
                                                       fp8_t* __restrict__ V8) {
  __shared__ __align__(16) unsigned char As[2 * 16384];
  __shared__ __align__(16) unsigned char Bs[2 * 16384];
  const int n = blockIdx.x;
  const int lane = threadIdx.x & 63, wave = threadIdx.x >> 6;
  const int wm = (wave >> 1) * 64, wn = (wave & 1) * 64;
  const int fr = lane & 15, q = lane >> 4;
  f32x4 acc[4][4]; zero_acc(acc);

  if (n < 1024) {
    const int xb = n & 7, yb = (n >> 3) & 31, b = n >> 8;
    const unsigned char* A  = (const unsigned char*)xnT8 + ((size_t)b * HW_ + yb * 128) * C_;
    const unsigned char* Bp = (const unsigned char*)wqkv8 + (size_t)xb * 128 * C_;
    gemm_bt_mx<false, 0x7F, 0x7B>(A, Bp, C_, C_, C_, acc, nullptr, As, Bs);
    const int r0 = yb * 128 + wm + (q << 2);
    const int cb = xb * 128 + wn;       // 64-col group base (true & stored)
    float bias[4];
#pragma unroll
    for (int j = 0; j < 4; ++j) bias[j] = qkv_b[cb + fr + j * 16];  // true cols
#pragma unroll
    for (int i = 0; i < 4; ++i)
#pragma unroll
      for (int r = 0; r < 4; ++r) {
        const int row = r0 + i * 16 + r;
        u32 dw = 0;
        dw = (u32)__builtin_amdgcn_cvt_pk_fp8_f32(acc[i][0][r] + bias[0],
                                                  acc[i][1][r] + bias[1], (int)dw, false);
        dw = (u32)__builtin_amdgcn_cvt_pk_fp8_f32(acc[i][2][r] + bias[2],
                                                  acc[i][3][r] + bias[3], (int)dw, true);
        *(u32*)((unsigned char*)QKt8 + ((size_t)b * HW_ + row) * 1024 + cb + fr * 4) = dw;
      }
  } else {
    const int m = n - 1024;
    const int xb = m & 31, yb = (m >> 5) & 3, b = m >> 7;
    const unsigned char* A  = (const unsigned char*)wqkv8 + (size_t)(1024 + yb * 128) * C_;
    const unsigned char* Bp = (const unsigned char*)xnT8 + ((size_t)b * HW_ + xb * 128) * C_;
    gemm_bt_mx<false, 0x7B, 0x7F>(A, Bp, C_, C_, C_, acc, nullptr, As, Bs);
    const int r0 = yb * 128 + wm + (q << 2);
    const int cb = xb * 128 + wn;       // hw 64-group base
#pragma unroll
    for (int i = 0; i < 4; ++i)
#pragma unroll
      for (int r = 0; r < 4; ++r) {
        const int row = r0 + i * 16 + r;        // c channel (row of V8)
        const float bias = qkv_b[1024 + row];
        u32 dw = 0;
        dw = (u32)__builtin_amdgcn_cvt_pk_fp8_f32(acc[i][0][r] + bias,
                                                  acc[i][1][r] + bias, (int)dw, false);
        dw = (u32)__builtin_amdgcn_cvt_pk_fp8_f32(acc[i][2][r] + bias,
                                                  acc[i][3][r] + bias, (int)dw, true);
        *(u32*)((unsigned char*)V8 + ((size_t)b * C_ + row) * HW_ + cb + fr * 4) = dw;
      }
  }
}

// P8[b][i][sigma-pos j] = fp8( 2^(scale*log2e * q_i.k_j - 4) )
// 256^2-tile 8-phase MX-fp8 GEMM (m201 template port). 1024 blocks, 8 waves.
// Per wave: 128x64 output (wave grid 2x4), acc[8][4]. Per K-tile (BK=128):
// 4 sub-phases of {12 ds_read_b128 | 4 cp16 of tile t+1 (phases 0,1 only)
// -> barrier -> lgkmcnt(0) -> 8 MFMA in setprio(1) -> [ph3: vmcnt(0)]
// -> barrier}. Chunk-rotation LDS layout identical to the 128^2 path.
__global__ void __launch_bounds__(512, 2) sexp_gemm_kernel(const fp8_t* __restrict__ QKt8,
                                                           fp8_t* __restrict__ P8) {
  __shared__ __align__(16) unsigned char As[2][256 * 128];
  __shared__ __align__(16) unsigned char Bs[2][256 * 128];

  // XCD-aware decode: 1024 blocks; 16 xb (K-panel) fastest within an XCD so
  // blocks sharing a Q row-panel are co-resident on one XCD's L2.
  const int n   = blockIdx.x;
  const int xcd = n & 7;
  const int p   = n >> 3;               // 0..127
  const int xb  = p & 15;               // K col panel (256 wide)
  const int grp = xcd * 8 + (p >> 4);   // 0..63 = (yb, b)
  const int yb  = grp & 15;             // Q row panel (256 tall)
  const int b   = grp >> 4;             // batch

  const unsigned char* QKtb = (const unsigned char*)QKt8 + (size_t)b * HW_ * 1024;
  const unsigned char* Agl = QKtb + (size_t)yb * 256 * 1024;        // Q rows
  const unsigned char* Bgl = QKtb + 512 + (size_t)xb * 256 * 1024;  // K rows

  const int tid  = threadIdx.x;
  const int lane = tid & 63;
  const int wave = tid >> 6;     // 0..7
  const int wm   = (wave >> 2) * 128;   // row half
  const int wn   = (wave & 3) * 64;     // col quarter
  const int fr   = lane & 15;
  const int q    = lane >> 4;
  const int co0  = ((2 * q     + fr) & 7) * 16;
  const int co1  = ((2 * q + 1 + fr) & 7) * 16;

  // staging: sweep s covers rows s*64 + (tid>>3); chunk-rotation mod 8.
  const int srow = tid >> 3;            // 0..63
  const int sch  = tid & 7;
  const int gch  = (((sch - srow) & 7)) * 16;

  f32x4 acc[8][4];
  {
    f32x4 z = {0.f, 0.f, 0.f, 0.f};
#pragma unroll
    for (int i = 0; i < 8; ++i)
#pragma unroll
      for (int j = 0; j < 4; ++j) acc[i][j] = z;
  }

  // prologue: stage tile 0 (8 cp16/thread), full drain (once per block)
#pragma unroll
  for (int s = 0; s < 4; ++s) {
    const int row = s * 64 + srow;
    cp16(Agl + (size_t)row * 1024 + gch, &As[0][row * 128 + sch * 16]);
    cp16(Bgl + (size_t)row * 1024 + gch, &Bs[0][row * 128 + sch * 16]);
  }
  asm volatile("s_waitcnt vmcnt(0)" ::: "memory");
  __builtin_amdgcn_s_barrier();

#pragma unroll 1
  for (int t = 0; t < 4; ++t) {
    const int cur = t & 1;
    const unsigned char* Ab = As[cur];
    const unsigned char* Bb = Bs[cur];
#pragma unroll
    for (int ph = 0; ph < 4; ++ph) {
      const int ah = (ph & 1) * 4;    // a-frag quadrant base
      const int bh = (ph >> 1) * 2;   // b-frag quadrant base
      // ds-load this phase's register subtile (12 x ds_read_b128)
      i32x8 a[4], bfr[2];
#pragma unroll
      for (int i = 0; i < 4; ++i) {
        const int ro = (wm + (ah + i) * 16 + fr) * 128;
        i32x4 lo = *(const i32x4*)(Ab + ro + co0);
        i32x4 hi = *(const i32x4*)(Ab + ro + co1);
        a[i] = __builtin_shufflevector(lo, hi, 0, 1, 2, 3, 4, 5, 6, 7);
      }
#pragma unroll
      for (int j = 0; j < 2; ++j) {
        const int ro = (wn + (bh + j) * 16 + fr) * 128;
        i32x4 lo = *(const i32x4*)(Bb + ro + co0);
        i32x4 hi = *(const i32x4*)(Bb + ro + co1);
        bfr[j] = __builtin_shufflevector(lo, hi, 0, 1, 2, 3, 4, 5, 6, 7);
      }
      // stage tile t+1 (4 cp16 in each of phases 0,1 -> fully issued >=2
      // phases before the tile-boundary vmcnt(0) => that wait is ~free)
      if (t < 3 && ph < 2) {
#pragma unroll
        for (int s = 0; s < 2; ++s) {
          const int row = (ph * 2 + s) * 64 + srow;
          cp16(Agl + (size_t)row * 1024 + (t + 1) * 128 + gch,
               &As[cur ^ 1][row * 128 + sch * 16]);
          cp16(Bgl + (size_t)row * 1024 + (t + 1) * 128 + gch,
               &Bs[cur ^ 1][row * 128 + sch * 16]);
        }
      }
      __builtin_amdgcn_s_barrier();
      asm volatile("s_waitcnt lgkmcnt(0)" ::: "memory");
      __builtin_amdgcn_sched_barrier(0);
      __builtin_amdgcn_s_setprio(1);
#pragma unroll
      for (int i = 0; i < 4; ++i)
#pragma unroll
        for (int j = 0; j < 2; ++j)
          acc[ah + i][bh + j] = __builtin_amdgcn_mfma_scale_f32_16x16x128_f8f6f4(
              a[i], bfr[j], acc[ah + i][bh + j], 0, 0, 0, 0x7F, 0, 0x7F);
      __builtin_amdgcn_s_setprio(0);
      if (ph == 3)
        asm volatile("s_waitcnt vmcnt(0)" ::: "memory");  // tile t+1 resident
      __builtin_amdgcn_s_barrier();
    }
  }

  // epilogue: exp2-fold + fp8 pack, sigma-packed 64-col groups (same math
  // and store pattern as the 128^2 version, 8 row-frags instead of 4)
  fp8_t* Pb = P8 + (size_t)b * HW_ * HW_;
  const int r0 = yb * 256 + wm + (q << 2);
  const int cb = xb * 256 + wn;
#pragma unroll
  for (int i = 0; i < 8; ++i)
#pragma unroll
    for (int r = 0; r < 4; ++r) {
      const int row = r0 + i * 16 + r;
      float e0 = fexp2(fmaf(acc[i][0][r], SEXPC_, -4.0f));
      float e1 = fexp2(fmaf(acc[i][1][r], SEXPC_, -4.0f));
      float e2 = fexp2(fmaf(acc[i][2][r], SEXPC_, -4.0f));
      float e3 = fexp2(fmaf(acc[i][3][r], SEXPC_, -4.0f));
      u32 dw = 0;
      dw = (u32)__builtin_amdgcn_cvt_pk_fp8_f32(e0, e1, (int)dw, false);
      dw = (u32)__builtin_amdgcn_cvt_pk_fp8_f32(e2, e3, (int)dw, true);
      *(u32*)((unsigned char*)Pb + (size_t)row * HW_ + cb + fr * 4) = dw;
    }
}

// hmT8[b][i][sigma-pos c] = fp8( 16 * (sum_j P8 * V8) / rowsum(P8) )
// MX-fp8 GEMM with ones-MFMA row sums; XCD-aware block remap for P L2 reuse.
__global__ void __launch_bounds__(256) pv_gemm_kernel(const fp8_t* __restrict__ P8,
                                                      const fp8_t* __restrict__ V8,
                                                      fp8_t* __restrict__ hmT8) {
  __shared__ __align__(16) unsigned char As[2 * 16384];
  __shared__ __align__(16) unsigned char Bs[2 * 16384];
  // decode swizzled block id: n = 512 blocks total
  const int n   = blockIdx.x;
  const int xcd = n & 7;           // XCD (round-robin heuristic)
  const int p   = n >> 3;          // 0..63, position within XCD
  const int xb  = p & 3;           // C panel (fastest -> adjacent blocks share P)
  const int grp = xcd * 16 + (p >> 2);  // 0..127 = (y,z) group
  const int yb  = grp & 31;        // HW panel
  const int b   = grp >> 5;        // batch

  const unsigned char* A  = (const unsigned char*)P8 + (size_t)b * HW_ * HW_ +
                            (size_t)yb * 128 * HW_;
  const unsigned char* Bp = (const unsigned char*)V8 + (size_t)b * C_ * HW_ +
                            (size_t)xb * 128 * HW_;
  fp8_t* hmTb = hmT8 + (size_t)b * HW_ * C_;

  f32x4 acc[4][4]; zero_acc(acc);
  f32x4 accl[4];
  {
    f32x4 z = {0.f, 0.f, 0.f, 0.f};
#pragma unroll
    for (int i = 0; i < 4; ++i) accl[i] = z;
  }
  gemm_bt_mx<true>(A, Bp, HW_, HW_, HW_, acc, accl, As, Bs);

  const int lane = threadIdx.x & 63, wave = threadIdx.x >> 6;
  const int wm = (wave >> 1) * 64, wn = (wave & 1) * 64;
  const int fr = lane & 15, q = lane >> 4;
  const int r0 = yb * 128 + wm + (q << 2);
  const int cb = xb * 128 + wn;   // c 64-group base (stored sigma-packed)
#pragma unroll
  for (int i = 0; i < 4; ++i)
#pragma unroll
    for (int r = 0; r < 4; ++r) {
      const int row = r0 + i * 16 + r;
      // x16 for fp8 range; undone by 2^-4 in proj. rcp: 1-ulp, fp8-invisible.
      const float rl = 16.f * __builtin_amdgcn_rcpf(accl[i][r]);
      u32 dw = 0;
      dw = (u32)__builtin_amdgcn_cvt_pk_fp8_f32(acc[i][0][r] * rl, acc[i][1][r] * rl, (int)dw, false);
      dw = (u32)__builtin_amdgcn_cvt_pk_fp8_f32(acc[i][2][r] * rl, acc[i][3][r] * rl, (int)dw, true);
      *(u32*)((unsigned char*)hmTb + (size_t)row * C_ + cb + fr * 4) = dw;
    }
}

// out[b][o][i] = x[b][o][i] + proj_b[o] + (wproj8*2^-4)(sigma) . (hmT8*2^-4)(sigma)
__global__ void __launch_bounds__(256) proj_gemm_kernel(const fp8_t* __restrict__ wproj8,
                                                        const fp8_t* __restrict__ hmT8,
                                                        const float* __restrict__ proj_b,
                                                        const float* __restrict__ x,
                                                        float* __restrict__ out) {
  __shared__ __align__(16) unsigned char As[2 * 16384];
  __shared__ __align__(16) unsigned char Bs[2 * 16384];
  const int b = blockIdx.z;
  f32x4 acc[4][4]; zero_acc(acc);
  const unsigned char* A  = (const unsigned char*)wproj8 + (size_t)blockIdx.y * 128 * C_;
  const unsigned char* Bp = (const unsigned char*)hmT8 + ((size_t)b * HW_ + blockIdx.x * 128) * C_;
  gemm_bt_mx<false, 0x7B, 0x7B>(A, Bp, C_, C_, C_, acc, nullptr, As, Bs);
  const int lane = threadIdx.x & 63, wave = threadIdx.x >> 6;
  const int wm = (wave >> 1) * 64, wn = (wave & 1) * 64;
  const int r0 = blockIdx.y * 128 + wm + ((lane >> 4) << 2);
  const int c0 = blockIdx.x * 128 + wn + (lane & 15);
#pragma unroll
  for (int i = 0; i < 4; ++i)
#pragma unroll
    for (int r = 0; r < 4; ++r) {
      const int row = r0 + i * 16 + r;
      const float bias = proj_b[row];
#pragma unroll
      for (int j = 0; j < 4; ++j) {
        const int col = c0 + j * 16;
        const size_t idx = ((size_t)b * C_ + row) * HW_ + col;
        out[idx] = x[idx] + bias + acc[i][j][r];
      }
    }
}

// ---------------- launch ----------------
// Workspace layout (bytes), total ~110 MB:
//   wqkv8  fp8 [1536][512] (x16)         786,432
//   wproj8 fp8 [512][512] (x16, sigma)   262,144
//   stats  f32 [128][2]                    1,024
//   xnT8   fp8 [4][4096][512]          8,388,608
//   QKt8   fp8 [4][4096][1024](sig)   16,777,216
//   V8     fp8 [4][512][4096] (sig)    8,388,608
//   hmT8   fp8 [4][4096][512] (x16,sig) 8,388,608
//   P8     fp8 [4][4096][4096](sig)   67,108,864
extern "C" void kernel_launch(void* const* d_in, const int* in_sizes, int n_in,
                              void* d_out, int out_size, void* d_ws, size_t ws_size,
                              hipStream_t stream) {
  const float* x      = (const float*)d_in[0];
  const float* norm_w = (const float*)d_in[1];
  const float* norm_b = (const float*)d_in[2];
  const float* qkv_w  = (const float*)d_in[3];
  const float* qkv_b  = (const float*)d_in[4];
  const float* proj_w = (const float*)d_in[5];
  const float* proj_b = (const float*)d_in[6];
  float* out = (float*)d_out;

  char* ws = (char*)d_ws;
  size_t o = 0;
  fp8_t* wqkv8  = (fp8_t*)(ws + o); o += (size_t)1536 * 512;
  fp8_t* wproj8 = (fp8_t*)(ws + o); o += (size_t)512 * 512;
  float* stats  = (float*)(ws + o); o += 128 * 2 * 4;
  fp8_t* xnT8   = (fp8_t*)(ws + o); o += (size_t)B_ * HW_ * C_;
  fp8_t* QKt8   = (fp8_t*)(ws + o); o += (size_t)B_ * HW_ * 1024;
  fp8_t* V8     = (fp8_t*)(ws + o); o += (size_t)B_ * C_ * HW_;
  fp8_t* hmT8   = (fp8_t*)(ws + o); o += (size_t)B_ * HW_ * C_;
  fp8_t* P8     = (fp8_t*)(ws + o); o += (size_t)B_ * HW_ * HW_;

  hipMemsetAsync(stats, 0, 128 * 2 * sizeof(float), stream);
  prep_kernel<<<2048, 256, 0, stream>>>(x, stats, qkv_w, proj_w, wqkv8, wproj8);
  norm_tr_kernel<<<dim3(HW_ / 64, C_ / 64, B_), 256, 0, stream>>>(x, stats, norm_w, norm_b, xnT8);
  qkv_gemm_kernel<<<1536, 256, 0, stream>>>(xnT8, wqkv8, qkv_b, QKt8, V8);
  sexp_gemm_kernel<<<1024, 512, 0, stream>>>(QKt8, P8);
  pv_gemm_kernel<<<512, 256, 0, stream>>>(P8, V8, hmT8);
  proj_gemm_kernel<<<dim3(HW_ / 128, C_ / 128, B_), 256, 0, stream>>>(
      wproj8, hmT8, proj_b, x, out);
}